// Round 23
// baseline (153.515 us; speedup 1.0000x reference)
//
#include <hip/hip_runtime.h>
#include <math.h>
#include <limits.h>

#define Bb 32
#define Tt 16384
#define Cc 128
#define Dd 256
#define Pp 2048
#define GMAX 4096
#define TP 16

// pid as XLA-jit computes it: divide(t,7) -> multiply(t, fl(1/7)).
// fl(1/7) = 0x3E124925. VERIFIED passing combination (R19) — do not touch.
__device__ __forceinline__ int PID(float t) {
  return (int)floorf(t * 0.14285714924335479736328125f);
}

// ---------------- Kernel A: XLA ReduceWindowRewriter radix-16 cumsum ----------
// VERIFIED producer replica (R19, absmax 0.0039). Unchanged.
__global__ __launch_bounds__(256) void scan_k(const float* __restrict__ td,
                                              int* __restrict__ starts,
                                              int* __restrict__ ngroups) {
  __shared__ float buf[Tt];
  __shared__ float S0[1024], P0[1024];
  __shared__ float S1[64],  P1[64];
  __shared__ float P2s[4];
  __shared__ int   cnt[256];

  const int b = blockIdx.x;
  const int tid = threadIdx.x;
  const float* row = td + (size_t)b * Tt;

  const float4* r4 = (const float4*)row;
  float4* b4 = (float4*)buf;
  for (int i = tid; i < Tt / 4; i += 256) b4[i] = r4[i];
  __syncthreads();

  for (int k = tid; k < 1024; k += 256) {
    const float* p = buf + k * 16;
    float s = p[0];
    #pragma unroll
    for (int j = 1; j < 16; ++j) s += p[j];
    S0[k] = s;
  }
  __syncthreads();

  if (tid < 64) {
    const float* p = S0 + tid * 16;
    float s = p[0];
    #pragma unroll
    for (int j = 1; j < 16; ++j) s += p[j];
    S1[tid] = s;
  }
  __syncthreads();

  if (tid == 0) {
    float run = 0.f;
    for (int m = 0; m < 4; ++m) {
      const float* p = S1 + m * 16;
      float s = p[0];
      #pragma unroll
      for (int j = 1; j < 16; ++j) s += p[j];
      run = (m == 0) ? s : run + s;
      P2s[m] = run;
    }
  }
  __syncthreads();

  if (tid < 64) {
    const int k2 = tid >> 4, j1 = tid & 15;
    const float* p = S1 + (k2 << 4);
    float s = p[0];
    for (int j = 1; j <= j1; ++j) s += p[j];
    P1[tid] = (k2 == 0) ? s : s + P2s[k2 - 1];
  }
  __syncthreads();

  for (int k = tid; k < 1024; k += 256) {
    const int k1 = k >> 4, j = k & 15;
    const float* p = S0 + (k1 << 4);
    float s = p[0];
    for (int jj = 1; jj <= j; ++jj) s += p[jj];
    P0[k] = (k1 == 0) ? s : s + P1[k1 - 1];
  }
  __syncthreads();

  const int base = tid * 64;
  int pprev0;
  if (tid == 0) pprev0 = INT_MIN;
  else {
    const int k = 4 * tid - 1;
    const float t = (k == 0) ? S0[0] : S0[k] + P0[k - 1];
    pprev0 = PID(t);
  }

  int pprev = pprev0, count = 0;
  for (int tk = 0; tk < 4; ++tk) {
    const int k = 4 * tid + tk;
    const float carry = (k == 0) ? 0.f : P0[k - 1];
    const float* p = buf + k * 16;
    float s = 0.f;
    #pragma unroll
    for (int j = 0; j < 16; ++j) {
      s = (j == 0) ? p[0] : s + p[j];
      const float t = (k == 0) ? s : s + carry;
      const int pid = PID(t);
      count += (pid != pprev);
      pprev = pid;
    }
  }
  cnt[tid] = count;
  __syncthreads();
  if (tid == 0) {
    int run = 0;
    for (int k = 0; k < 256; ++k) { int c = cnt[k]; cnt[k] = run; run += c; }
  }
  __syncthreads();

  int r = cnt[tid];
  pprev = pprev0;
  int* stb = starts + b * GMAX;
  for (int tk = 0; tk < 4; ++tk) {
    const int k = 4 * tid + tk;
    const float carry = (k == 0) ? 0.f : P0[k - 1];
    const float* p = buf + k * 16;
    float s = 0.f;
    #pragma unroll
    for (int j = 0; j < 16; ++j) {
      s = (j == 0) ? p[0] : s + p[j];
      const float t = (k == 0) ? s : s + carry;
      const int pid = PID(t);
      if (pid != pprev) stb[r++] = k * 16 + j;
      pprev = pid;
    }
  }
  if (tid == 255) {
    ngroups[b] = r;
    stb[r] = Tt;
  }
}

// ---------------- Kernel B1: group means, 2 patch slots per wave --------------
// A/B change vs R22: 2 slots/wave x 4-deep independent chains = 8 predicated
// float4 loads in flight per lane (was 2). One-wave blocks keep TLP maximal.
// lane = (row-parity r2, channel-quad cq); full wave covers 1KB contiguous.
__global__ __launch_bounds__(64) void means_k(const float* __restrict__ x,
                                              const int* __restrict__ starts,
                                              const int* __restrict__ ngroups,
                                              float* __restrict__ means) {
  const int blk = blockIdx.x;           // Bb * Pp/2 blocks
  const int b = blk >> 10;
  const int pbase = (blk & 1023) * 2;   // slots pbase, pbase+1
  const int lane = threadIdx.x;
  const int ng = ngroups[b];
  const int off = Pp - ng;
  const int r2 = lane >> 5;             // row parity
  const int cq = lane & 31;             // channel quad
  const int* st = starts + b * GMAX;

  int s[2], n[2];
  #pragma unroll
  for (int k = 0; k < 2; ++k) {
    const int g = pbase + k - off;
    if (g >= 0) { s[k] = st[g]; n[k] = st[g + 1] - s[k]; }
    else        { s[k] = 0;     n[k] = 0; }
  }

  float4 a[2][4];
  #pragma unroll
  for (int k = 0; k < 2; ++k)
    #pragma unroll
    for (int c = 0; c < 4; ++c) a[k][c] = make_float4(0.f, 0.f, 0.f, 0.f);

  const int nmax = max(n[0], n[1]);
  const float* xb = x + ((size_t)b * Tt) * Cc + 4 * cq;

  for (int i = r2; i < nmax; i += 8) {  // 8 rows per iter (4 chains x parity 2)
    #pragma unroll
    for (int c = 0; c < 4; ++c) {
      const int ii = i + 2 * c;
      #pragma unroll
      for (int k = 0; k < 2; ++k) {
        if (ii < n[k]) {
          const float4 v = *(const float4*)(xb + (size_t)(s[k] + ii) * Cc);
          a[k][c].x += v.x; a[k][c].y += v.y; a[k][c].z += v.z; a[k][c].w += v.w;
        }
      }
    }
  }

  #pragma unroll
  for (int k = 0; k < 2; ++k) {
    float4 t0 = a[k][0], t1 = a[k][1], t2 = a[k][2], t3 = a[k][3];
    t0.x += t1.x; t0.y += t1.y; t0.z += t1.z; t0.w += t1.w;
    t2.x += t3.x; t2.y += t3.y; t2.z += t3.z; t2.w += t3.w;
    t0.x += t2.x; t0.y += t2.y; t0.z += t2.z; t0.w += t2.w;
    t0.x += __shfl_xor(t0.x, 32);
    t0.y += __shfl_xor(t0.y, 32);
    t0.z += __shfl_xor(t0.z, 32);
    t0.w += __shfl_xor(t0.w, 32);
    if (r2 == 0) {
      float4 m = make_float4(0.f, 0.f, 0.f, 0.f);
      if (n[k] > 0) {
        const float fn = (float)n[k];
        m = make_float4(t0.x / fn, t0.y / fn, t0.z / fn, t0.w / fn);
      }
      *(float4*)(means + ((size_t)b * Pp + pbase + k) * Cc + 4 * cq) = m;
    }
  }
}

// ---------------- Kernel B2: dense projection out = means*W + b ---------------
// Unchanged from R22 (clean A/B attribution).
__global__ __launch_bounds__(256) void gemm_k(const float* __restrict__ means,
                                              const float* __restrict__ Wm,
                                              const float* __restrict__ bias,
                                              const int* __restrict__ ngroups,
                                              float* __restrict__ out_patches,
                                              float* __restrict__ out_valid) {
  const int blk = blockIdx.x;
  const int b = blk >> 7;
  const int pt = (blk & 127) * TP;
  const int tid = threadIdx.x;
  const int ng = ngroups[b];
  const int off = Pp - ng;

  const float bias_v = bias[tid];
  const size_t obase = ((size_t)b * Pp + pt) * Dd + tid;

  if (tid < TP)
    out_valid[(size_t)b * Pp + pt + tid] = (pt + tid >= off) ? 1.0f : 0.0f;

  if (pt + TP <= off) {
    #pragma unroll
    for (int j = 0; j < TP; ++j) out_patches[obase + (size_t)j * Dd] = bias_v;
    return;
  }

  __shared__ float mean_l[TP][Cc];
  {
    const float4* src = (const float4*)(means + ((size_t)b * Pp + pt) * Cc);
    float4* dst = (float4*)&mean_l[0][0];
    dst[tid] = src[tid];
    dst[tid + 256] = src[tid + 256];
  }
  __syncthreads();

  float acc[16];
  #pragma unroll
  for (int j = 0; j < 16; ++j) acc[j] = 0.f;

  const float* wp = Wm + tid;
  for (int q = 0; q < Cc / 4; ++q) {
    const float w0 = wp[(4 * q + 0) * Dd];
    const float w1 = wp[(4 * q + 1) * Dd];
    const float w2 = wp[(4 * q + 2) * Dd];
    const float w3 = wp[(4 * q + 3) * Dd];
    #pragma unroll
    for (int j = 0; j < 16; ++j) {
      const float4 m = *(const float4*)(&mean_l[j][4 * q]);
      float a = acc[j];
      a = fmaf(m.x, w0, a);
      a = fmaf(m.y, w1, a);
      a = fmaf(m.z, w2, a);
      a = fmaf(m.w, w3, a);
      acc[j] = a;
    }
  }

  #pragma unroll
  for (int j = 0; j < 16; ++j)
    out_patches[obase + (size_t)j * Dd] = acc[j] + bias_v;
}

extern "C" void kernel_launch(void* const* d_in, const int* in_sizes, int n_in,
                              void* d_out, int out_size, void* d_ws, size_t ws_size,
                              hipStream_t stream) {
  const float* x    = (const float*)d_in[0];
  const float* td   = (const float*)d_in[1];
  const float* Wm   = (const float*)d_in[2];
  const float* bias = (const float*)d_in[3];
  float* out = (float*)d_out;

  int*   starts  = (int*)d_ws;                              // 512 KB
  int*   ngroups = (int*)((char*)d_ws + 524288);            // 128 B
  float* means   = (float*)((char*)d_ws + (1 << 20));       // 33.5 MB @ 1MB

  scan_k<<<Bb, 256, 0, stream>>>(td, starts, ngroups);
  means_k<<<Bb * (Pp / 2), 64, 0, stream>>>(x, starts, ngroups, means);
  gemm_k<<<Bb * (Pp / TP), 256, 0, stream>>>(means, Wm, bias, ngroups,
                                             out, out + (size_t)Bb * Pp * Dd);
}

// Round 24
// 105.579 us; speedup vs baseline: 1.4540x; 1.4540x over previous
//
#include <hip/hip_runtime.h>
#include <hip/hip_bf16.h>
#include <math.h>
#include <limits.h>

#define Bb 32
#define Tt 16384
#define Cc 128
#define Dd 256
#define Pp 2048
#define GMAX 4096
#define TP 16

typedef __attribute__((ext_vector_type(8))) short bf16x8;
typedef __attribute__((ext_vector_type(4))) float f32x4;

// float -> bf16 (RNE, no NaN handling needed: data is finite)
__device__ __forceinline__ unsigned short f2bf(float f) {
  unsigned u = __float_as_uint(f);
  return (unsigned short)((u + 0x7FFFu + ((u >> 16) & 1u)) >> 16);
}

// pid as XLA-jit computes it: divide(t,7) -> multiply(t, fl(1/7)).
// fl(1/7) = 0x3E124925. VERIFIED passing combination (R19) — do not touch.
__device__ __forceinline__ int PID(float t) {
  return (int)floorf(t * 0.14285714924335479736328125f);
}

// ---------------- Kernel A: XLA ReduceWindowRewriter radix-16 cumsum ----------
// VERIFIED producer replica (R19, absmax 0.0039). Unchanged.
__global__ __launch_bounds__(256) void scan_k(const float* __restrict__ td,
                                              int* __restrict__ starts,
                                              int* __restrict__ ngroups) {
  __shared__ float buf[Tt];
  __shared__ float S0[1024], P0[1024];
  __shared__ float S1[64],  P1[64];
  __shared__ float P2s[4];
  __shared__ int   cnt[256];

  const int b = blockIdx.x;
  const int tid = threadIdx.x;
  const float* row = td + (size_t)b * Tt;

  const float4* r4 = (const float4*)row;
  float4* b4 = (float4*)buf;
  for (int i = tid; i < Tt / 4; i += 256) b4[i] = r4[i];
  __syncthreads();

  for (int k = tid; k < 1024; k += 256) {
    const float* p = buf + k * 16;
    float s = p[0];
    #pragma unroll
    for (int j = 1; j < 16; ++j) s += p[j];
    S0[k] = s;
  }
  __syncthreads();

  if (tid < 64) {
    const float* p = S0 + tid * 16;
    float s = p[0];
    #pragma unroll
    for (int j = 1; j < 16; ++j) s += p[j];
    S1[tid] = s;
  }
  __syncthreads();

  if (tid == 0) {
    float run = 0.f;
    for (int m = 0; m < 4; ++m) {
      const float* p = S1 + m * 16;
      float s = p[0];
      #pragma unroll
      for (int j = 1; j < 16; ++j) s += p[j];
      run = (m == 0) ? s : run + s;
      P2s[m] = run;
    }
  }
  __syncthreads();

  if (tid < 64) {
    const int k2 = tid >> 4, j1 = tid & 15;
    const float* p = S1 + (k2 << 4);
    float s = p[0];
    for (int j = 1; j <= j1; ++j) s += p[j];
    P1[tid] = (k2 == 0) ? s : s + P2s[k2 - 1];
  }
  __syncthreads();

  for (int k = tid; k < 1024; k += 256) {
    const int k1 = k >> 4, j = k & 15;
    const float* p = S0 + (k1 << 4);
    float s = p[0];
    for (int jj = 1; jj <= j; ++jj) s += p[jj];
    P0[k] = (k1 == 0) ? s : s + P1[k1 - 1];
  }
  __syncthreads();

  const int base = tid * 64;
  int pprev0;
  if (tid == 0) pprev0 = INT_MIN;
  else {
    const int k = 4 * tid - 1;
    const float t = (k == 0) ? S0[0] : S0[k] + P0[k - 1];
    pprev0 = PID(t);
  }

  int pprev = pprev0, count = 0;
  for (int tk = 0; tk < 4; ++tk) {
    const int k = 4 * tid + tk;
    const float carry = (k == 0) ? 0.f : P0[k - 1];
    const float* p = buf + k * 16;
    float s = 0.f;
    #pragma unroll
    for (int j = 0; j < 16; ++j) {
      s = (j == 0) ? p[0] : s + p[j];
      const float t = (k == 0) ? s : s + carry;
      const int pid = PID(t);
      count += (pid != pprev);
      pprev = pid;
    }
  }
  cnt[tid] = count;
  __syncthreads();
  if (tid == 0) {
    int run = 0;
    for (int k = 0; k < 256; ++k) { int c = cnt[k]; cnt[k] = run; run += c; }
  }
  __syncthreads();

  int r = cnt[tid];
  pprev = pprev0;
  int* stb = starts + b * GMAX;
  for (int tk = 0; tk < 4; ++tk) {
    const int k = 4 * tid + tk;
    const float carry = (k == 0) ? 0.f : P0[k - 1];
    const float* p = buf + k * 16;
    float s = 0.f;
    #pragma unroll
    for (int j = 0; j < 16; ++j) {
      s = (j == 0) ? p[0] : s + p[j];
      const float t = (k == 0) ? s : s + carry;
      const int pid = PID(t);
      if (pid != pprev) stb[r++] = k * 16 + j;
      pprev = pid;
    }
  }
  if (tid == 255) {
    ngroups[b] = r;
    stb[r] = Tt;
  }
}

// ---------------- Kernel P: pack W into bf16 MFMA B-fragment order ------------
// Wp[tile=nt*4+kt][lane][j] = bf16(W[kt*32+(lane>>4)*8+j][nt*16+(lane&15)])
__global__ __launch_bounds__(256) void packw_k(const float* __restrict__ Wm,
                                               unsigned short* __restrict__ Wp) {
  const int t = blockIdx.x * 256 + threadIdx.x;   // 4096 threads
  const int tile = t >> 6, lane = t & 63;
  const int nt = tile >> 2, kt = tile & 3;
  const int kbase = kt * 32 + (lane >> 4) * 8;
  const int n = nt * 16 + (lane & 15);
  unsigned short tmp[8];
  #pragma unroll
  for (int j = 0; j < 8; ++j)
    tmp[j] = f2bf(Wm[(size_t)(kbase + j) * Dd + n]);
  *(uint4*)(Wp + (size_t)tile * 512 + lane * 8) = *(const uint4*)tmp;
}

// ---------------- Kernel B1: group means (R22 structure), bf16 output ---------
__global__ __launch_bounds__(64) void means_k(const float* __restrict__ x,
                                              const int* __restrict__ starts,
                                              const int* __restrict__ ngroups,
                                              unsigned short* __restrict__ means) {
  const int blk = blockIdx.x;
  const int b = blk >> 11;
  const int p = blk & (Pp - 1);
  const int lane = threadIdx.x;
  const int ng = ngroups[b];
  const int off = Pp - ng;
  const int g = p - off;
  unsigned short* mp = means + ((size_t)b * Pp + p) * Cc;

  if (g < 0) {                         // padding slot -> zero mean
    *(unsigned int*)(mp + 2 * lane) = 0u;
    return;
  }

  const int* st = starts + b * GMAX;
  const int s = st[g], e = st[g + 1];
  const int n = e - s;
  const int r2 = lane >> 5;
  const int cq = lane & 31;

  const float* xp = x + ((size_t)b * Tt + s) * Cc + 4 * cq;
  float4 a0 = make_float4(0.f, 0.f, 0.f, 0.f);
  float4 a1 = make_float4(0.f, 0.f, 0.f, 0.f);
  int i = r2;
  for (; i + 2 < n; i += 4) {
    const float4 v0 = *(const float4*)(xp + (size_t)i * Cc);
    const float4 v1 = *(const float4*)(xp + (size_t)(i + 2) * Cc);
    a0.x += v0.x; a0.y += v0.y; a0.z += v0.z; a0.w += v0.w;
    a1.x += v1.x; a1.y += v1.y; a1.z += v1.z; a1.w += v1.w;
  }
  if (i < n) {
    const float4 v = *(const float4*)(xp + (size_t)i * Cc);
    a0.x += v.x; a0.y += v.y; a0.z += v.z; a0.w += v.w;
  }
  a0.x += a1.x; a0.y += a1.y; a0.z += a1.z; a0.w += a1.w;
  a0.x += __shfl_xor(a0.x, 32);
  a0.y += __shfl_xor(a0.y, 32);
  a0.z += __shfl_xor(a0.z, 32);
  a0.w += __shfl_xor(a0.w, 32);
  if (r2 == 0) {
    const float fn = (float)n;
    unsigned short q[4];
    q[0] = f2bf(a0.x / fn); q[1] = f2bf(a0.y / fn);
    q[2] = f2bf(a0.z / fn); q[3] = f2bf(a0.w / fn);
    *(uint2*)(mp + 4 * cq) = *(const uint2*)q;   // 8B store
  }
}

// ---------------- Kernel B2: MFMA projection out = means*W + b ----------------
// 16 patches x 256 D per block; 4 waves, wave w owns n-tiles [4w, 4w+4).
// A (means) staged in LDS bf16 [16][128] with XOR swizzle (G4): byte ^=
// ((row&7)<<4) -> fragment ds_read_b128 <=2-way conflicts. B (Wp) fragment-
// packed in global (64KB, L2-hot), coalesced b128 per lane.
// C/D layout (VERIFIED m89): patch = (lane>>4)*4 + reg, d = nt*16 + (lane&15).
__global__ __launch_bounds__(256) void gemm_k(const unsigned short* __restrict__ means,
                                              const unsigned short* __restrict__ Wp,
                                              const float* __restrict__ bias,
                                              const int* __restrict__ ngroups,
                                              float* __restrict__ out_patches,
                                              float* __restrict__ out_valid) {
  const int blk = blockIdx.x;
  const int b = blk >> 7;
  const int pt = (blk & 127) * TP;
  const int tid = threadIdx.x;
  const int ng = ngroups[b];
  const int off = Pp - ng;

  if (tid < TP)
    out_valid[(size_t)b * Pp + pt + tid] = (pt + tid >= off) ? 1.0f : 0.0f;

  if (pt + TP <= off) {                // whole tile is padding -> bias
    const float bias_v = bias[tid];
    const size_t obase = ((size_t)b * Pp + pt) * Dd + tid;
    #pragma unroll
    for (int j = 0; j < TP; ++j) out_patches[obase + (size_t)j * Dd] = bias_v;
    return;
  }

  __shared__ unsigned short alds[TP * Cc];   // 4KB, xor-swizzled rows of 256B
  {
    const int row = tid >> 4, seg = tid & 15;
    const uint4 v = *(const uint4*)(means + ((size_t)(b * Pp + pt + row)) * Cc + seg * 8);
    *(uint4*)((char*)alds + row * 256 + ((seg * 16) ^ ((row & 7) << 4))) = v;
  }
  __syncthreads();

  const int w = tid >> 6, l = tid & 63;
  const int mrow = l & 15;             // A row for this lane's fragment reads

  bf16x8 a[4];
  #pragma unroll
  for (int kt = 0; kt < 4; ++kt) {
    const int boff = ((kt * 4 + (l >> 4)) * 16) ^ ((mrow & 7) << 4);
    a[kt] = *(const bf16x8*)((const char*)alds + mrow * 256 + boff);
  }

  f32x4 acc[4];
  #pragma unroll
  for (int nt4 = 0; nt4 < 4; ++nt4) acc[nt4] = (f32x4){0.f, 0.f, 0.f, 0.f};

  #pragma unroll
  for (int nt4 = 0; nt4 < 4; ++nt4) {
    const int nt = w * 4 + nt4;
    #pragma unroll
    for (int kt = 0; kt < 4; ++kt) {
      const bf16x8 bf = *(const bf16x8*)(Wp + (size_t)(nt * 4 + kt) * 512 + l * 8);
      acc[nt4] = __builtin_amdgcn_mfma_f32_16x16x32_bf16(a[kt], bf, acc[nt4], 0, 0, 0);
    }
  }

  #pragma unroll
  for (int nt4 = 0; nt4 < 4; ++nt4) {
    const int d = (w * 4 + nt4) * 16 + mrow;
    const float bv = bias[d];
    const size_t ob = ((size_t)b * Pp + pt + (l >> 4) * 4) * Dd + d;
    #pragma unroll
    for (int j = 0; j < 4; ++j)
      out_patches[ob + (size_t)j * Dd] = acc[nt4][j] + bv;
  }
}

extern "C" void kernel_launch(void* const* d_in, const int* in_sizes, int n_in,
                              void* d_out, int out_size, void* d_ws, size_t ws_size,
                              hipStream_t stream) {
  const float* x    = (const float*)d_in[0];
  const float* td   = (const float*)d_in[1];
  const float* Wm   = (const float*)d_in[2];
  const float* bias = (const float*)d_in[3];
  float* out = (float*)d_out;

  int*            starts  = (int*)d_ws;                               // 512 KB
  int*            ngroups = (int*)((char*)d_ws + 524288);             // 128 B
  unsigned short* means   = (unsigned short*)((char*)d_ws + (1 << 20));      // 16.8 MB
  unsigned short* Wp      = (unsigned short*)((char*)d_ws + (20 << 20));     // 64 KB

  scan_k<<<Bb, 256, 0, stream>>>(td, starts, ngroups);
  packw_k<<<16, 256, 0, stream>>>(Wm, Wp);
  means_k<<<Bb * Pp, 64, 0, stream>>>(x, starts, ngroups, means);
  gemm_k<<<Bb * (Pp / TP), 256, 0, stream>>>(means, Wp, bias, ngroups,
                                             out, out + (size_t)Bb * Pp * Dd);
}